// Round 7
// baseline (282.902 us; speedup 1.0000x reference)
//
#include <hip/hip_runtime.h>
#include <hip/hip_bf16.h>
#include <cstddef>

// ---------- types ----------
typedef _Float16 f16x8 __attribute__((ext_vector_type(8)));
typedef _Float16 f16x4 __attribute__((ext_vector_type(4)));
typedef _Float16 f16x2 __attribute__((ext_vector_type(2)));
typedef float    f32x4 __attribute__((ext_vector_type(4)));
typedef unsigned int u32x4 __attribute__((ext_vector_type(4)));

#define NTOK   4096        // 64*64
#define DIM    256
#define QBLK   32
#define KVBLK  64
// SCALE = 32^-0.5 ; fold SCALE*log2(e) into Q so softmax uses exp2 directly
#define QSCALE 0.2550530069938472f

static __device__ __forceinline__ unsigned int pkh(float a, float b) {
    f16x2 h; h.x = (_Float16)a; h.y = (_Float16)b;
    return __builtin_bit_cast(unsigned int, h);
}

// ---------- kernel 1: positional-embedding table (64 x 256 f32) ----------
// reference truncates to the x-part: pe[n][c] = sin/cos(x * freq), x from n&63
__global__ void pe_kernel(float* __restrict__ pe) {
    int id  = blockIdx.x * 256 + threadIdx.x;      // 0..16383
    int col = id >> 8;                             // 0..63
    int c   = id & 255;
    float x = col * (2.0f / 63.0f) - 1.0f;
    int ci  = (c < 128) ? c : (c - 128);
    float freq = expf(ci * (-9.2103403719761836f / 127.0f)); // -ln(10000)/127
    float arg  = x * freq;
    pe[id] = (c < 128) ? sinf(arg) : cosf(arg);
}

// ---------- kernel 2: transpose (b,c,n)->(b,n,c), add pe, scale, cast f16 ----------
__global__ void prep_qk_kernel(const float* __restrict__ qin, const float* __restrict__ kin,
                               const float* __restrict__ pe,
                               _Float16* __restrict__ Qh, _Float16* __restrict__ Kh) {
    __shared__ float tile[32][33];
    int tx = threadIdx.x, ty = threadIdx.y;        // 32 x 8
    int nb = blockIdx.x, cb = blockIdx.y, z = blockIdx.z;
    int b = z >> 1, tensor = z & 1;
    const float* src = tensor ? kin : qin;
    _Float16*    dst = tensor ? Kh : Qh;
    float scale = tensor ? 1.0f : QSCALE;
    size_t base = (size_t)b * DIM * NTOK;
#pragma unroll
    for (int i2 = 0; i2 < 4; i2++) {
        int c = cb * 32 + ty + 8 * i2;
        tile[ty + 8 * i2][tx] = src[base + (size_t)c * NTOK + nb * 32 + tx];
    }
    __syncthreads();
#pragma unroll
    for (int i2 = 0; i2 < 4; i2++) {
        int n = nb * 32 + ty + 8 * i2;
        int c = cb * 32 + tx;
        float v2 = (tile[tx][ty + 8 * i2] + pe[(n & 63) * DIM + c]) * scale;
        dst[(size_t)b * NTOK * DIM + (size_t)n * DIM + c] = (_Float16)v2;
    }
}

// ---------- kernel 3: V cast only, keep (b,c,n) layout (= V^T, what PV wants) ----------
__global__ void prep_v_kernel(const float* __restrict__ vin, _Float16* __restrict__ Vh) {
    int idx = blockIdx.x * 256 + threadIdx.x;      // 524288 float4's
    float4 x = ((const float4*)vin)[idx];
    f16x4 h;
    h.x = (_Float16)x.x; h.y = (_Float16)x.y; h.z = (_Float16)x.z; h.w = (_Float16)x.w;
    ((f16x4*)Vh)[idx] = h;
}

// ---------- kernel 4: fused flash attention (transposed compute) ----------
// grid 256 blocks (1/CU), 4 waves/block. Block owns 32 q rows; waves KV-split mod 4.
// S^T = mfma(A=K, B=Q^T) ; O^T = mfma(A=V^T, B=P^T). 16x16x32 f16 MFMA.
__global__ __launch_bounds__(256, 1)
void attn_kernel(const _Float16* __restrict__ Qh, const _Float16* __restrict__ Kh,
                 const _Float16* __restrict__ Vh, float* __restrict__ out) {
    __shared__ float obuf[DIM * 33];               // [c][q] padded, 33.8 KB
    __shared__ float mbuf[4][32];
    __shared__ float lbuf[4][32];
    __shared__ float linv[32];

    const int tid  = threadIdx.x;
    const int w    = tid >> 6;
    const int lane = tid & 63;
    const int q    = lane & 15;                    // col within 16-wide block / row-within-16
    const int g    = lane >> 4;                    // k-group

    // XCD swizzle: 32 blocks per XCD all on the same batch -> K+V (4MiB) fits that L2
    const int xb = blockIdx.x & 7;
    const int ib = blockIdx.x >> 3;
    const int b  = xb >> 2;
    const int q0 = ((xb & 3) * 32 + ib) * QBLK;    // q-tile base, 0..4064

    const _Float16* Qp = Qh + ((size_t)(b * NTOK + q0)) * DIM;
    const _Float16* Kp = Kh + (size_t)b * NTOK * DIM;
    const _Float16* Vp = Vh + (size_t)b * NTOK * DIM;

    // Q B-frags, persistent: B[k=c][col=q], lane reads 8 contiguous c
    f16x8 qf[2][8];
#pragma unroll
    for (int qb = 0; qb < 2; qb++)
#pragma unroll
        for (int ks = 0; ks < 8; ks++)
            qf[qb][ks] = *(const f16x8*)(Qp + (qb * 16 + q) * DIM + ks * 32 + g * 8);

    f32x4 of[16][2];                               // O^T acc: [cblock][qblock]
#pragma unroll
    for (int cb = 0; cb < 16; cb++)
#pragma unroll
        for (int qb = 0; qb < 2; qb++)
            of[cb][qb] = (f32x4){0.f, 0.f, 0.f, 0.f};
    float m[2] = {-1e30f, -1e30f};
    float l[2] = {0.f, 0.f};

    const int  srcA   = ((2 * g) & 3) * 16 + q;
    const int  srcB   = ((2 * g + 1) & 3) * 16 + q;
    const bool lowsel = (g < 2);

#pragma unroll 1
    for (int t = w; t < NTOK / KVBLK; t += 4) {
        // ---- S^T = K * Q^T over D=256 ----
        f32x4 sc[4][2];
#pragma unroll
        for (int rb = 0; rb < 4; rb++)
#pragma unroll
            for (int qb = 0; qb < 2; qb++)
                sc[rb][qb] = (f32x4){0.f, 0.f, 0.f, 0.f};
        const _Float16* Kt = Kp + (size_t)(t * KVBLK + q) * DIM + g * 8;
#pragma unroll
        for (int ks = 0; ks < 8; ks++) {
            f16x8 kf[4];
#pragma unroll
            for (int rb = 0; rb < 4; rb++)
                kf[rb] = *(const f16x8*)(Kt + rb * 16 * DIM + ks * 32);
#pragma unroll
            for (int rb = 0; rb < 4; rb++) {
                sc[rb][0] = __builtin_amdgcn_mfma_f32_16x16x32_f16(kf[rb], qf[0][ks], sc[rb][0], 0, 0, 0);
                sc[rb][1] = __builtin_amdgcn_mfma_f32_16x16x32_f16(kf[rb], qf[1][ks], sc[rb][1], 0, 0, 0);
            }
        }
        // ---- online softmax (scores already in log2 domain via QSCALE) ----
        float cf[2];
#pragma unroll
        for (int qb = 0; qb < 2; qb++) {
            float tmx = sc[0][qb][0];
#pragma unroll
            for (int rb = 0; rb < 4; rb++)
#pragma unroll
                for (int i = 0; i < 4; i++) tmx = fmaxf(tmx, sc[rb][qb][i]);
            tmx = fmaxf(tmx, __shfl_xor(tmx, 16));
            tmx = fmaxf(tmx, __shfl_xor(tmx, 32));
            float mn = fmaxf(m[qb], tmx);
            cf[qb] = exp2f(m[qb] - mn);
            m[qb]  = mn;
            float ls = 0.f;
#pragma unroll
            for (int rb = 0; rb < 4; rb++)
#pragma unroll
                for (int i = 0; i < 4; i++) {
                    float p = exp2f(sc[rb][qb][i] - mn);
                    sc[rb][qb][i] = p;
                    ls += p;
                }
            ls += __shfl_xor(ls, 16);
            ls += __shfl_xor(ls, 32);
            l[qb] = l[qb] * cf[qb] + ls;
        }
#pragma unroll
        for (int cb = 0; cb < 16; cb++)
#pragma unroll
            for (int qb = 0; qb < 2; qb++)
#pragma unroll
                for (int i = 0; i < 4; i++) of[cb][qb][i] *= cf[qb];

        // ---- P^T -> f16 B-frags (cross 4-lane-group redistribute), then O^T += V^T * P^T ----
#pragma unroll
        for (int ks2 = 0; ks2 < 2; ks2++) {
            f16x8 bfq[2];
#pragma unroll
            for (int qb = 0; qb < 2; qb++) {
                unsigned int a01_0 = pkh(sc[ks2 * 2 + 0][qb][0], sc[ks2 * 2 + 0][qb][1]);
                unsigned int a23_0 = pkh(sc[ks2 * 2 + 0][qb][2], sc[ks2 * 2 + 0][qb][3]);
                unsigned int a01_1 = pkh(sc[ks2 * 2 + 1][qb][0], sc[ks2 * 2 + 1][qb][1]);
                unsigned int a23_1 = pkh(sc[ks2 * 2 + 1][qb][2], sc[ks2 * 2 + 1][qb][3]);
                unsigned int r0a = (unsigned int)__shfl((int)a01_0, srcA);
                unsigned int r0b = (unsigned int)__shfl((int)a01_1, srcA);
                unsigned int r1a = (unsigned int)__shfl((int)a23_0, srcA);
                unsigned int r1b = (unsigned int)__shfl((int)a23_1, srcA);
                unsigned int r2a = (unsigned int)__shfl((int)a01_0, srcB);
                unsigned int r2b = (unsigned int)__shfl((int)a01_1, srcB);
                unsigned int r3a = (unsigned int)__shfl((int)a23_0, srcB);
                unsigned int r3b = (unsigned int)__shfl((int)a23_1, srcB);
                u32x4 bu;
                bu.x = lowsel ? r0a : r0b;
                bu.y = lowsel ? r1a : r1b;
                bu.z = lowsel ? r2a : r2b;
                bu.w = lowsel ? r3a : r3b;
                bfq[qb] = __builtin_bit_cast(f16x8, bu);
            }
            const _Float16* Vt = Vp + (size_t)q * NTOK + t * KVBLK + ks2 * 32 + g * 8;
#pragma unroll
            for (int cb = 0; cb < 16; cb++) {
                f16x8 vf = *(const f16x8*)(Vt + (size_t)cb * 16 * NTOK);
                of[cb][0] = __builtin_amdgcn_mfma_f32_16x16x32_f16(vf, bfq[0], of[cb][0], 0, 0, 0);
                of[cb][1] = __builtin_amdgcn_mfma_f32_16x16x32_f16(vf, bfq[1], of[cb][1], 0, 0, 0);
            }
        }
    }

    // ---- cross-wave merge ----
    if (lane < 16) {
        mbuf[w][lane] = m[0]; mbuf[w][16 + lane] = m[1];
        lbuf[w][lane] = l[0]; lbuf[w][16 + lane] = l[1];
    }
    __syncthreads();
    float cfw[2];
    {
        float M0 = mbuf[0][q], M1 = mbuf[0][16 + q];
#pragma unroll
        for (int ww = 1; ww < 4; ww++) {
            M0 = fmaxf(M0, mbuf[ww][q]);
            M1 = fmaxf(M1, mbuf[ww][16 + q]);
        }
        cfw[0] = exp2f(m[0] - M0);
        cfw[1] = exp2f(m[1] - M1);
        if (w == 0 && lane < 16) {
            float L0 = 0.f, L1 = 0.f;
#pragma unroll
            for (int ww = 0; ww < 4; ww++) {
                L0 += lbuf[ww][lane] * exp2f(mbuf[ww][lane] - M0);
                L1 += lbuf[ww][16 + lane] * exp2f(mbuf[ww][16 + lane] - M1);
            }
            linv[lane] = 1.f / L0;
            linv[16 + lane] = 1.f / L1;
        }
    }
    for (int r = 0; r < 4; r++) {
        if (w == r) {
#pragma unroll
            for (int cb = 0; cb < 16; cb++)
#pragma unroll
                for (int qb = 0; qb < 2; qb++)
#pragma unroll
                    for (int i = 0; i < 4; i++) {
                        int c  = cb * 16 + g * 4 + i;
                        int qq = qb * 16 + q;
                        float val = of[cb][qb][i] * cfw[qb];
                        if (r == 0) obuf[c * 33 + qq] = val;
                        else        obuf[c * 33 + qq] += val;
                    }
        }
        __syncthreads();
    }
    // ---- epilogue: coalesced float4 stores of out[b][q][c] ----
    float* Ob = out + ((size_t)(b * NTOK + q0)) * DIM;
    int c0 = (tid & 63) * 4;
    int wq = tid >> 6;
#pragma unroll
    for (int qq = 0; qq < 8; qq++) {
        int qrow = qq * 4 + wq;
        float inv = linv[qrow];
        float4 o;
        o.x = obuf[(c0 + 0) * 33 + qrow] * inv;
        o.y = obuf[(c0 + 1) * 33 + qrow] * inv;
        o.z = obuf[(c0 + 2) * 33 + qrow] * inv;
        o.w = obuf[(c0 + 3) * 33 + qrow] * inv;
        *(float4*)(Ob + (size_t)qrow * DIM + c0) = o;
    }
}

// ---------- launcher ----------
extern "C" void kernel_launch(void* const* d_in, const int* in_sizes, int n_in,
                              void* d_out, int out_size, void* d_ws, size_t ws_size,
                              hipStream_t stream) {
    const float* qin = (const float*)d_in[0];
    const float* kin = (const float*)d_in[1];
    const float* vin = (const float*)d_in[2];
    float* outp = (float*)d_out;

    char* ws = (char*)d_ws;
    float*    pe = (float*)ws;                                   // 64 KB
    _Float16* Qh = (_Float16*)(ws + 65536);                      // 4 MiB
    _Float16* Kh = (_Float16*)(ws + 65536 + (1u << 22));         // 4 MiB
    _Float16* Vh = (_Float16*)(ws + 65536 + (2u << 22));         // 4 MiB

    pe_kernel<<<dim3(64), dim3(256), 0, stream>>>(pe);
    prep_qk_kernel<<<dim3(128, 8, 4), dim3(32, 8), 0, stream>>>(qin, kin, pe, Qh, Kh);
    prep_v_kernel<<<dim3(2048), dim3(256), 0, stream>>>(vin, Vh);
    attn_kernel<<<dim3(256), dim3(256), 0, stream>>>(Qh, Kh, Vh, outp);
}

// Round 8
// 237.906 us; speedup vs baseline: 1.1891x; 1.1891x over previous
//
#include <hip/hip_runtime.h>
#include <hip/hip_bf16.h>
#include <cstddef>

// ---------- types ----------
typedef _Float16 f16x8 __attribute__((ext_vector_type(8)));
typedef _Float16 f16x4 __attribute__((ext_vector_type(4)));
typedef _Float16 f16x2 __attribute__((ext_vector_type(2)));
typedef float    f32x4 __attribute__((ext_vector_type(4)));
typedef unsigned int u32x2 __attribute__((ext_vector_type(2)));

#define NTOK   4096        // 64*64
#define DIM    256
#define QBLK   32          // q rows per block
#define KVT    128         // KV rows per cooperative tile
// SCALE = 32^-0.5 ; fold SCALE*log2(e) into Q so softmax uses exp2 directly
#define QSCALE 0.2550530069938472f

static __device__ __forceinline__ unsigned int pkh(float a, float b) {
    f16x2 h; h.x = (_Float16)a; h.y = (_Float16)b;
    return __builtin_bit_cast(unsigned int, h);
}

// ---------- kernel 1: positional-embedding table (64 x 256 f32) ----------
__global__ void pe_kernel(float* __restrict__ pe) {
    int id  = blockIdx.x * 256 + threadIdx.x;
    int col = id >> 8;
    int c   = id & 255;
    float x = col * (2.0f / 63.0f) - 1.0f;
    int ci  = (c < 128) ? c : (c - 128);
    float freq = expf(ci * (-9.2103403719761836f / 127.0f));
    float arg  = x * freq;
    pe[id] = (c < 128) ? sinf(arg) : cosf(arg);
}

// ---------- kernel 2: transpose (b,c,n)->(b,n,c), add pe, scale, cast f16 ----------
// v2: 64c x 32n tile, vectorized f16x8 stores (was scalar 2B stores)
__global__ void prep_qk_kernel(const float* __restrict__ qin, const float* __restrict__ kin,
                               const float* __restrict__ pe,
                               _Float16* __restrict__ Qh, _Float16* __restrict__ Kh) {
    __shared__ float tile[64][33];
    int tid = threadIdx.x;                 // 256
    int nb = blockIdx.x, cb = blockIdx.y, z = blockIdx.z;
    int b = z >> 1, tensor = z & 1;
    const float* src = tensor ? kin : qin;
    _Float16*    dst = tensor ? Kh : Qh;
    float scale = tensor ? 1.0f : QSCALE;
    size_t base = (size_t)b * DIM * NTOK;
    int n0 = nb * 32, c0 = cb * 64;
    int tx = tid & 31, cy = tid >> 5;
#pragma unroll
    for (int r = 0; r < 8; r++)
        tile[cy + r * 8][tx] = src[base + (size_t)(c0 + cy + r * 8) * NTOK + n0 + tx];
    __syncthreads();
    int nl = tid >> 3, cc = tid & 7;
    int n = n0 + nl;
    const float* per = pe + (n & 63) * DIM + c0 + cc * 8;
    float4 p0 = *(const float4*)(per);
    float4 p1 = *(const float4*)(per + 4);
    float pv[8] = {p0.x, p0.y, p0.z, p0.w, p1.x, p1.y, p1.z, p1.w};
    f16x8 o;
#pragma unroll
    for (int j = 0; j < 8; j++)
        o[j] = (_Float16)((tile[cc * 8 + j][nl] + pv[j]) * scale);
    *(f16x8*)(dst + (size_t)b * NTOK * DIM + (size_t)n * DIM + c0 + cc * 8) = o;
}

// ---------- kernel 3: V cast only, keep (b,c,n) layout (= V^T) ----------
__global__ void prep_v_kernel(const float* __restrict__ vin, _Float16* __restrict__ Vh) {
    int idx = blockIdx.x * 256 + threadIdx.x;
    float4 x = ((const float4*)vin)[idx];
    f16x4 h;
    h.x = (_Float16)x.x; h.y = (_Float16)x.y; h.z = (_Float16)x.z; h.w = (_Float16)x.w;
    ((f16x4*)Vh)[idx] = h;
}

// ---------- kernel 4: cooperative-tile flash attention ----------
// 256 blocks x 8 waves. Block owns 32 q rows; all waves share one KVT=128 tile.
// Wave w: QK rows [16w,16w+16); shared-m via LDS; P^T via dbuf LDS; PV c-slice [32w,32w+32).
__global__ __launch_bounds__(512, 2)
void attn_kernel(const _Float16* __restrict__ Qh, const _Float16* __restrict__ Kh,
                 const _Float16* __restrict__ Vh, float* __restrict__ out) {
    __shared__ __align__(16) _Float16 Pbuf[2][32][136];   // [buf][q][k] 136=128+8 pad
    __shared__ float mpart[8][32];
    __shared__ float lbuf[8][32];

    const int tid  = threadIdx.x;
    const int w    = tid >> 6;            // 0..7
    const int lane = tid & 63;
    const int q    = lane & 15;
    const int g    = lane >> 4;

    // XCD swizzle: 32 blocks per XCD on same batch -> K+V (4MiB) fits that L2
    const int xb = blockIdx.x & 7;
    const int ib = blockIdx.x >> 3;       // 0..31
    const int b  = xb >> 2;
    const int q0 = ((xb & 3) * 32 + ib) * QBLK;

    const _Float16* Qp = Qh + ((size_t)(b * NTOK + q0)) * DIM;
    const _Float16* Kp = Kh + (size_t)b * NTOK * DIM;
    const _Float16* Vp = Vh + (size_t)b * NTOK * DIM;

    // persistent Q B-frags: B[k=c][col=q-row]
    f16x8 qf[2][8];
#pragma unroll
    for (int qb = 0; qb < 2; qb++)
#pragma unroll
        for (int ks = 0; ks < 8; ks++)
            qf[qb][ks] = *(const f16x8*)(Qp + (qb * 16 + q) * DIM + ks * 32 + g * 8);

    f32x4 of[2][2];                       // [cb][qb]; c = w*32 + cb*16 + g*4 + i
#pragma unroll
    for (int cb = 0; cb < 2; cb++)
#pragma unroll
        for (int qb = 0; qb < 2; qb++)
            of[cb][qb] = (f32x4){0.f, 0.f, 0.f, 0.f};
    float m[2] = {-1e30f, -1e30f};
    float l[2] = {0.f, 0.f};

    const _Float16* Kw = Kp + (size_t)(w * 16 + q) * DIM + g * 8;
    const _Float16* Vw = Vp + (size_t)(w * 32 + q) * NTOK + g * 8;

#pragma unroll 1
    for (int t = 0; t < NTOK / KVT; ++t) {
        // ---- QK: wave w computes S^T rows [16w,16w+16) x 32 q-cols ----
        f32x4 sc[2] = {(f32x4){0.f,0.f,0.f,0.f}, (f32x4){0.f,0.f,0.f,0.f}};
        const _Float16* Kt = Kw + (size_t)t * KVT * DIM;
#pragma unroll
        for (int ks = 0; ks < 8; ks++) {
            f16x8 kf = *(const f16x8*)(Kt + ks * 32);
            sc[0] = __builtin_amdgcn_mfma_f32_16x16x32_f16(kf, qf[0][ks], sc[0], 0, 0, 0);
            sc[1] = __builtin_amdgcn_mfma_f32_16x16x32_f16(kf, qf[1][ks], sc[1], 0, 0, 0);
        }
        // per-wave max over its 16 k-rows (4 elems + reduce across g)
        float tmx[2];
#pragma unroll
        for (int qb = 0; qb < 2; qb++) {
            float tm = fmaxf(fmaxf(sc[qb][0], sc[qb][1]), fmaxf(sc[qb][2], sc[qb][3]));
            tm = fmaxf(tm, __shfl_xor(tm, 16));
            tm = fmaxf(tm, __shfl_xor(tm, 32));
            tmx[qb] = tm;
        }
        if (lane < 16) {
            mpart[w][lane]      = tmx[0];
            mpart[w][16 + lane] = tmx[1];
        }
        __syncthreads();                          // barrier 1: mpart visible
        float cfv[2];
        _Float16 (*Pb)[136] = Pbuf[t & 1];
#pragma unroll
        for (int qb = 0; qb < 2; qb++) {
            float mt = mpart[0][qb * 16 + q];
#pragma unroll
            for (int ww = 1; ww < 8; ww++) mt = fmaxf(mt, mpart[ww][qb * 16 + q]);
            float mn = fmaxf(m[qb], mt);
            cfv[qb] = exp2f(m[qb] - mn);
            m[qb] = mn;
            float p0 = exp2f(sc[qb][0] - mn);
            float p1 = exp2f(sc[qb][1] - mn);
            float p2 = exp2f(sc[qb][2] - mn);
            float p3 = exp2f(sc[qb][3] - mn);
            float ls = (p0 + p1) + (p2 + p3);
            ls += __shfl_xor(ls, 16);
            ls += __shfl_xor(ls, 32);
            l[qb] = l[qb] * cfv[qb] + ls;
            u32x2 pk; pk.x = pkh(p0, p1); pk.y = pkh(p2, p3);
            *(u32x2*)((char*)&Pb[qb * 16 + q][0] + (w * 16 + g * 4) * 2) = pk;
        }
#pragma unroll
        for (int cb = 0; cb < 2; cb++)
#pragma unroll
            for (int qb = 0; qb < 2; qb++)
#pragma unroll
                for (int i = 0; i < 4; i++) of[cb][qb][i] *= cfv[qb];
        __syncthreads();                          // barrier 2: P visible
        // ---- PV: wave w accumulates c-slice [32w,32w+32) over this tile ----
        const _Float16* Vt = Vw + t * KVT;
#pragma unroll
        for (int ks = 0; ks < 4; ks++) {
            f16x8 pf[2];
            pf[0] = *(const f16x8*)(&Pb[q][ks * 32 + g * 8]);
            pf[1] = *(const f16x8*)(&Pb[16 + q][ks * 32 + g * 8]);
#pragma unroll
            for (int cb = 0; cb < 2; cb++) {
                f16x8 vf = *(const f16x8*)(Vt + (size_t)cb * 16 * NTOK + ks * 32);
                of[cb][0] = __builtin_amdgcn_mfma_f32_16x16x32_f16(vf, pf[0], of[cb][0], 0, 0, 0);
                of[cb][1] = __builtin_amdgcn_mfma_f32_16x16x32_f16(vf, pf[1], of[cb][1], 0, 0, 0);
            }
        }
    }

    // ---- final: sum per-wave l partials (shared m sequence -> additive) ----
    if (lane < 16) {
        lbuf[w][lane]      = l[0];
        lbuf[w][16 + lane] = l[1];
    }
    __syncthreads();
    float linv[2];
#pragma unroll
    for (int qb = 0; qb < 2; qb++) {
        float s = lbuf[0][qb * 16 + q];
#pragma unroll
        for (int ww = 1; ww < 8; ww++) s += lbuf[ww][qb * 16 + q];
        linv[qb] = 1.f / s;
    }
    // ---- epilogue: each wave stores its own c-slice ----
    float* Ob = out + ((size_t)(b * NTOK + q0)) * DIM;
#pragma unroll
    for (int cb = 0; cb < 2; cb++)
#pragma unroll
        for (int qb = 0; qb < 2; qb++) {
            float4 o;
            o.x = of[cb][qb][0] * linv[qb];
            o.y = of[cb][qb][1] * linv[qb];
            o.z = of[cb][qb][2] * linv[qb];
            o.w = of[cb][qb][3] * linv[qb];
            *(float4*)(Ob + (size_t)(qb * 16 + q) * DIM + w * 32 + cb * 16 + g * 4) = o;
        }
}

// ---------- launcher ----------
extern "C" void kernel_launch(void* const* d_in, const int* in_sizes, int n_in,
                              void* d_out, int out_size, void* d_ws, size_t ws_size,
                              hipStream_t stream) {
    const float* qin = (const float*)d_in[0];
    const float* kin = (const float*)d_in[1];
    const float* vin = (const float*)d_in[2];
    float* outp = (float*)d_out;

    char* ws = (char*)d_ws;
    float*    pe = (float*)ws;                                   // 64 KB
    _Float16* Qh = (_Float16*)(ws + 65536);                      // 4 MiB
    _Float16* Kh = (_Float16*)(ws + 65536 + (1u << 22));         // 4 MiB
    _Float16* Vh = (_Float16*)(ws + 65536 + (2u << 22));         // 4 MiB

    pe_kernel<<<dim3(64), dim3(256), 0, stream>>>(pe);
    prep_qk_kernel<<<dim3(128, 4, 4), dim3(256), 0, stream>>>(qin, kin, pe, Qh, Kh);
    prep_v_kernel<<<dim3(2048), dim3(256), 0, stream>>>(vin, Vh);
    attn_kernel<<<dim3(256), dim3(512), 0, stream>>>(Qh, Kh, Vh, outp);
}

// Round 10
// 195.919 us; speedup vs baseline: 1.4440x; 1.2143x over previous
//
#include <hip/hip_runtime.h>
#include <hip/hip_bf16.h>
#include <cstddef>

// ---------- types ----------
typedef _Float16 f16x8 __attribute__((ext_vector_type(8)));
typedef _Float16 f16x4 __attribute__((ext_vector_type(4)));
typedef _Float16 f16x2 __attribute__((ext_vector_type(2)));
typedef float    f32x4 __attribute__((ext_vector_type(4)));
typedef unsigned int u32x2 __attribute__((ext_vector_type(2)));

#define NTOK   4096        // 64*64
#define DIM    256
#define QBLK   32          // q rows per block
#define KVT    128         // KV rows per cooperative tile
// SCALE = 32^-0.5 ; fold SCALE*log2(e) into Q so softmax uses exp2 directly
#define QSCALE 0.2550530069938472f

static __device__ __forceinline__ unsigned int pkh(float a, float b) {
    f16x2 h; h.x = (_Float16)a; h.y = (_Float16)b;
    return __builtin_bit_cast(unsigned int, h);
}

// ---------- kernel 1: positional-embedding table (64 x 256 f32) ----------
__global__ void pe_kernel(float* __restrict__ pe) {
    int id  = blockIdx.x * 256 + threadIdx.x;
    int col = id >> 8;
    int c   = id & 255;
    float x = col * (2.0f / 63.0f) - 1.0f;
    int ci  = (c < 128) ? c : (c - 128);
    float freq = expf(ci * (-9.2103403719761836f / 127.0f));
    float arg  = x * freq;
    pe[id] = (c < 128) ? sinf(arg) : cosf(arg);
}

// ---------- kernel 2: transpose (b,c,n)->(b,n,c), add pe, scale, cast f16 ----------
__global__ void prep_qk_kernel(const float* __restrict__ qin, const float* __restrict__ kin,
                               const float* __restrict__ pe,
                               _Float16* __restrict__ Qh, _Float16* __restrict__ Kh) {
    __shared__ float tile[64][33];
    int tid = threadIdx.x;                 // 256
    int nb = blockIdx.x, cb = blockIdx.y, z = blockIdx.z;
    int b = z >> 1, tensor = z & 1;
    const float* src = tensor ? kin : qin;
    _Float16*    dst = tensor ? Kh : Qh;
    float scale = tensor ? 1.0f : QSCALE;
    size_t base = (size_t)b * DIM * NTOK;
    int n0 = nb * 32, c0 = cb * 64;
    int tx = tid & 31, cy = tid >> 5;
#pragma unroll
    for (int r = 0; r < 8; r++)
        tile[cy + r * 8][tx] = src[base + (size_t)(c0 + cy + r * 8) * NTOK + n0 + tx];
    __syncthreads();
    int nl = tid >> 3, cc = tid & 7;
    int n = n0 + nl;
    const float* per = pe + (n & 63) * DIM + c0 + cc * 8;
    float4 p0 = *(const float4*)(per);
    float4 p1 = *(const float4*)(per + 4);
    float pv[8] = {p0.x, p0.y, p0.z, p0.w, p1.x, p1.y, p1.z, p1.w};
    f16x8 o;
#pragma unroll
    for (int j = 0; j < 8; j++)
        o[j] = (_Float16)((tile[cc * 8 + j][nl] + pv[j]) * scale);
    *(f16x8*)(dst + (size_t)b * NTOK * DIM + (size_t)n * DIM + c0 + cc * 8) = o;
}

// ---------- kernel 3: V cast only, keep (b,c,n) layout (= V^T) ----------
__global__ void prep_v_kernel(const float* __restrict__ vin, _Float16* __restrict__ Vh) {
    int idx = blockIdx.x * 256 + threadIdx.x;
    float4 x = ((const float4*)vin)[idx];
    f16x4 h;
    h.x = (_Float16)x.x; h.y = (_Float16)x.y; h.z = (_Float16)x.z; h.w = (_Float16)x.w;
    ((f16x4*)Vh)[idx] = h;
}

// ---------- kernel 4: cooperative-tile flash attention, v3 ----------
// 256 blocks x 8 waves. Q staged in LDS (remat-friendly). K double-buffered in
// regs (prefetch t+1 during t). V prefetched at iter top. Barriers drain
// lgkmcnt only (global loads stay in flight across them).
__global__ __launch_bounds__(512, 2)
void attn_kernel(const _Float16* __restrict__ Qh, const _Float16* __restrict__ Kh,
                 const _Float16* __restrict__ Vh, float* __restrict__ out) {
    __shared__ __align__(16) _Float16 Qlds[32][264];      // pad 8 f16 -> 2-way-free
    __shared__ __align__(16) _Float16 Pbuf[2][32][136];   // [buf][q][kv]
    __shared__ float mpart[8][32];
    __shared__ float lbuf[8][32];

    const int tid  = threadIdx.x;
    const int w    = tid >> 6;            // 0..7
    const int lane = tid & 63;
    const int q    = lane & 15;
    const int g    = lane >> 4;

    // XCD swizzle: 32 blocks per XCD on same batch -> K+V (4MiB) fits that L2
    const int xb = blockIdx.x & 7;
    const int ib = blockIdx.x >> 3;       // 0..31
    const int b  = xb >> 2;
    const int q0 = ((xb & 3) * 32 + ib) * QBLK;

    const _Float16* Qp = Qh + ((size_t)(b * NTOK + q0)) * DIM;
    const _Float16* Kp = Kh + (size_t)b * NTOK * DIM;
    const _Float16* Vp = Vh + (size_t)b * NTOK * DIM;

    // ---- stage Q tile (32x256) into LDS, coalesced ----
    {
        int r = tid >> 4, ci = (tid & 15) * 16;
        const _Float16* srcq = Qp + (size_t)r * DIM + ci;
        f16x8 a0 = *(const f16x8*)(srcq);
        f16x8 a1 = *(const f16x8*)(srcq + 8);
        *(f16x8*)(&Qlds[r][ci])     = a0;
        *(f16x8*)(&Qlds[r][ci + 8]) = a1;
    }
    __syncthreads();

    // persistent Q B-frags from LDS (remat = cheap ds_read if demoted)
    f16x8 qf[2][8];
#pragma unroll
    for (int qb = 0; qb < 2; qb++)
#pragma unroll
        for (int ks = 0; ks < 8; ks++)
            qf[qb][ks] = *(const f16x8*)(&Qlds[qb * 16 + q][ks * 32 + g * 8]);

    f32x4 of[2][2];                       // [cb][qb]; c = w*32 + cb*16 + g*4 + i
#pragma unroll
    for (int cb = 0; cb < 2; cb++)
#pragma unroll
        for (int qb = 0; qb < 2; qb++)
            of[cb][qb] = (f32x4){0.f, 0.f, 0.f, 0.f};
    float m[2] = {-1e30f, -1e30f};
    float l[2] = {0.f, 0.f};

    const _Float16* Kw = Kp + (size_t)(w * 16 + q) * DIM + g * 8;
    const _Float16* Vw = Vp + (size_t)(w * 32 + q) * NTOK + g * 8;

    f16x8 kfA[8], kfB[8];
#pragma unroll
    for (int ks = 0; ks < 8; ks++)
        kfA[ks] = *(const f16x8*)(Kw + ks * 32);

#define ATTN_STEP(KC, KN, PIDX, T) do {                                           \
    /* prefetch V(T): used after softmax */                                       \
    f16x8 vf0[4], vf1[4];                                                         \
    { const _Float16* Vt = Vw + (size_t)(T) * KVT;                                \
      _Pragma("unroll") for (int ks = 0; ks < 4; ks++) {                          \
        vf0[ks] = *(const f16x8*)(Vt + ks * 32);                                  \
        vf1[ks] = *(const f16x8*)(Vt + (size_t)16 * NTOK + ks * 32); } }          \
    /* QK with resident K frags */                                                \
    f32x4 sc0 = {0.f,0.f,0.f,0.f}, sc1 = {0.f,0.f,0.f,0.f};                       \
    _Pragma("unroll") for (int ks = 0; ks < 8; ks++) {                            \
        sc0 = __builtin_amdgcn_mfma_f32_16x16x32_f16(KC[ks], qf[0][ks], sc0, 0, 0, 0); \
        sc1 = __builtin_amdgcn_mfma_f32_16x16x32_f16(KC[ks], qf[1][ks], sc1, 0, 0, 0); } \
    /* prefetch K(T+1): used next iteration */                                    \
    { int tn = (T) + 1; if (tn > 31) tn = 31;                                     \
      const _Float16* Ktn = Kw + (size_t)tn * KVT * DIM;                          \
      _Pragma("unroll") for (int ks = 0; ks < 8; ks++)                            \
        KN[ks] = *(const f16x8*)(Ktn + ks * 32); }                                \
    /* wave-local max, publish */                                                 \
    float tm0 = fmaxf(fmaxf(sc0[0], sc0[1]), fmaxf(sc0[2], sc0[3]));              \
    tm0 = fmaxf(tm0, __shfl_xor(tm0, 16)); tm0 = fmaxf(tm0, __shfl_xor(tm0, 32)); \
    float tm1 = fmaxf(fmaxf(sc1[0], sc1[1]), fmaxf(sc1[2], sc1[3]));              \
    tm1 = fmaxf(tm1, __shfl_xor(tm1, 16)); tm1 = fmaxf(tm1, __shfl_xor(tm1, 32)); \
    if (lane < 16) { mpart[w][lane] = tm0; mpart[w][16 + lane] = tm1; }           \
    asm volatile("s_waitcnt lgkmcnt(0)" ::: "memory");                            \
    __builtin_amdgcn_s_barrier();                                                 \
    /* shared max, exp, P write */                                                \
    float mt0 = mpart[0][q], mt1 = mpart[0][16 + q];                              \
    _Pragma("unroll") for (int ww = 1; ww < 8; ww++) {                            \
        mt0 = fmaxf(mt0, mpart[ww][q]); mt1 = fmaxf(mt1, mpart[ww][16 + q]); }    \
    float mn0 = fmaxf(m[0], mt0), mn1 = fmaxf(m[1], mt1);                         \
    float cf0 = exp2f(m[0] - mn0), cf1 = exp2f(m[1] - mn1);                       \
    m[0] = mn0; m[1] = mn1;                                                       \
    { float p0 = exp2f(sc0[0]-mn0), p1 = exp2f(sc0[1]-mn0);                       \
      float p2 = exp2f(sc0[2]-mn0), p3 = exp2f(sc0[3]-mn0);                       \
      float ls = (p0+p1)+(p2+p3);                                                 \
      ls += __shfl_xor(ls, 16); ls += __shfl_xor(ls, 32);                         \
      l[0] = l[0]*cf0 + ls;                                                       \
      u32x2 pk; pk.x = pkh(p0, p1); pk.y = pkh(p2, p3);                           \
      *(u32x2*)((char*)&Pbuf[PIDX][q][0] + (w*16 + g*4)*2) = pk; }                \
    { float p0 = exp2f(sc1[0]-mn1), p1 = exp2f(sc1[1]-mn1);                       \
      float p2 = exp2f(sc1[2]-mn1), p3 = exp2f(sc1[3]-mn1);                       \
      float ls = (p0+p1)+(p2+p3);                                                 \
      ls += __shfl_xor(ls, 16); ls += __shfl_xor(ls, 32);                         \
      l[1] = l[1]*cf1 + ls;                                                       \
      u32x2 pk; pk.x = pkh(p0, p1); pk.y = pkh(p2, p3);                           \
      *(u32x2*)((char*)&Pbuf[PIDX][16 + q][0] + (w*16 + g*4)*2) = pk; }           \
    _Pragma("unroll") for (int i = 0; i < 4; i++) {                               \
        of[0][0][i] *= cf0; of[0][1][i] *= cf1;                                   \
        of[1][0][i] *= cf0; of[1][1][i] *= cf1; }                                 \
    asm volatile("s_waitcnt lgkmcnt(0)" ::: "memory");                            \
    __builtin_amdgcn_s_barrier();                                                 \
    /* PV: c-slice [32w, 32w+32) */                                               \
    _Pragma("unroll") for (int ks = 0; ks < 4; ks++) {                            \
        f16x8 pf0 = *(const f16x8*)(&Pbuf[PIDX][q][ks*32 + g*8]);                 \
        f16x8 pf1 = *(const f16x8*)(&Pbuf[PIDX][16 + q][ks*32 + g*8]);            \
        of[0][0] = __builtin_amdgcn_mfma_f32_16x16x32_f16(vf0[ks], pf0, of[0][0], 0, 0, 0); \
        of[0][1] = __builtin_amdgcn_mfma_f32_16x16x32_f16(vf0[ks], pf1, of[0][1], 0, 0, 0); \
        of[1][0] = __builtin_amdgcn_mfma_f32_16x16x32_f16(vf1[ks], pf0, of[1][0], 0, 0, 0); \
        of[1][1] = __builtin_amdgcn_mfma_f32_16x16x32_f16(vf1[ks], pf1, of[1][1], 0, 0, 0); } \
} while (0)

#pragma unroll 1
    for (int t = 0; t < NTOK / KVT; t += 2) {
        ATTN_STEP(kfA, kfB, 0, t);
        ATTN_STEP(kfB, kfA, 1, t + 1);
    }
#undef ATTN_STEP

    // ---- final: sum per-wave l partials (shared m sequence -> additive) ----
    if (lane < 16) {
        lbuf[w][lane]      = l[0];
        lbuf[w][16 + lane] = l[1];
    }
    __syncthreads();
    float linv[2];
#pragma unroll
    for (int qb = 0; qb < 2; qb++) {
        float s = lbuf[0][qb * 16 + q];
#pragma unroll
        for (int ww = 1; ww < 8; ww++) s += lbuf[ww][qb * 16 + q];
        linv[qb] = 1.f / s;
    }
    // ---- epilogue: each wave stores its own c-slice ----
    float* Ob = out + ((size_t)(b * NTOK + q0)) * DIM;
#pragma unroll
    for (int cb = 0; cb < 2; cb++)
#pragma unroll
        for (int qb = 0; qb < 2; qb++) {
            float4 o;
            o.x = of[cb][qb][0] * linv[qb];
            o.y = of[cb][qb][1] * linv[qb];
            o.z = of[cb][qb][2] * linv[qb];
            o.w = of[cb][qb][3] * linv[qb];
            *(float4*)(Ob + (size_t)(qb * 16 + q) * DIM + w * 32 + cb * 16 + g * 4) = o;
        }
}

// ---------- launcher ----------
extern "C" void kernel_launch(void* const* d_in, const int* in_sizes, int n_in,
                              void* d_out, int out_size, void* d_ws, size_t ws_size,
                              hipStream_t stream) {
    const float* qin = (const float*)d_in[0];
    const float* kin = (const float*)d_in[1];
    const float* vin = (const float*)d_in[2];
    float* outp = (float*)d_out;

    char* ws = (char*)d_ws;
    float*    pe = (float*)ws;                                   // 64 KB
    _Float16* Qh = (_Float16*)(ws + 65536);                      // 4 MiB
    _Float16* Kh = (_Float16*)(ws + 65536 + (1u << 22));         // 4 MiB
    _Float16* Vh = (_Float16*)(ws + 65536 + (2u << 22));         // 4 MiB

    pe_kernel<<<dim3(64), dim3(256), 0, stream>>>(pe);
    prep_qk_kernel<<<dim3(128, 4, 4), dim3(256), 0, stream>>>(qin, kin, pe, Qh, Kh);
    prep_v_kernel<<<dim3(2048), dim3(256), 0, stream>>>(vin, Vh);
    attn_kernel<<<dim3(256), dim3(512), 0, stream>>>(Qh, Kh, Vh, outp);
}

// Round 12
// 169.512 us; speedup vs baseline: 1.6689x; 1.1558x over previous
//
#include <hip/hip_runtime.h>
#include <hip/hip_bf16.h>
#include <cstddef>

// ---------- types ----------
typedef _Float16 f16x8 __attribute__((ext_vector_type(8)));
typedef _Float16 f16x4 __attribute__((ext_vector_type(4)));
typedef _Float16 f16x2 __attribute__((ext_vector_type(2)));
typedef float    f32x4 __attribute__((ext_vector_type(4)));
typedef unsigned int u32x2 __attribute__((ext_vector_type(2)));

#define NTOK   4096        // 64*64
#define DIM    256
#define KVT    64          // KV rows per cooperative tile
#define NT     (NTOK / KVT)
// SCALE = 32^-0.5 ; fold SCALE*log2(e) into Q so softmax uses exp2 directly
#define QSCALE 0.2550530069938472f

static __device__ __forceinline__ unsigned int pkh(float a, float b) {
    f16x2 h; h.x = (_Float16)a; h.y = (_Float16)b;
    return __builtin_bit_cast(unsigned int, h);
}

// ---------- kernel 1: positional-embedding table (64 x 256 f32) ----------
__global__ void pe_kernel(float* __restrict__ pe) {
    int id  = blockIdx.x * 256 + threadIdx.x;
    int col = id >> 8;
    int c   = id & 255;
    float x = col * (2.0f / 63.0f) - 1.0f;
    int ci  = (c < 128) ? c : (c - 128);
    float freq = expf(ci * (-9.2103403719761836f / 127.0f));
    float arg  = x * freq;
    pe[id] = (c < 128) ? sinf(arg) : cosf(arg);
}

// ---------- kernel 2: transpose (b,c,n)->(b,n,c), add pe, scale, cast f16 ----------
__global__ void prep_qk_kernel(const float* __restrict__ qin, const float* __restrict__ kin,
                               const float* __restrict__ pe,
                               _Float16* __restrict__ Qh, _Float16* __restrict__ Kh) {
    __shared__ float tile[64][33];
    int tid = threadIdx.x;                 // 256
    int nb = blockIdx.x, cb = blockIdx.y, z = blockIdx.z;
    int b = z >> 1, tensor = z & 1;
    const float* src = tensor ? kin : qin;
    _Float16*    dst = tensor ? Kh : Qh;
    float scale = tensor ? 1.0f : QSCALE;
    size_t base = (size_t)b * DIM * NTOK;
    int n0 = nb * 32, c0 = cb * 64;
    int tx = tid & 31, cy = tid >> 5;
#pragma unroll
    for (int r = 0; r < 8; r++)
        tile[cy + r * 8][tx] = src[base + (size_t)(c0 + cy + r * 8) * NTOK + n0 + tx];
    __syncthreads();
    int nl = tid >> 3, cc = tid & 7;
    int n = n0 + nl;
    const float* per = pe + (n & 63) * DIM + c0 + cc * 8;
    float4 p0 = *(const float4*)(per);
    float4 p1 = *(const float4*)(per + 4);
    float pv[8] = {p0.x, p0.y, p0.z, p0.w, p1.x, p1.y, p1.z, p1.w};
    f16x8 o;
#pragma unroll
    for (int j = 0; j < 8; j++)
        o[j] = (_Float16)((tile[cc * 8 + j][nl] + pv[j]) * scale);
    *(f16x8*)(dst + (size_t)b * NTOK * DIM + (size_t)n * DIM + c0 + cc * 8) = o;
}

// ---------- kernel 3: V cast only, keep (b,c,n) layout (= V^T) ----------
__global__ void prep_v_kernel(const float* __restrict__ vin, _Float16* __restrict__ Vh) {
    int idx = blockIdx.x * 256 + threadIdx.x;
    float4 x = ((const float4*)vin)[idx];
    f16x4 h;
    h.x = (_Float16)x.x; h.y = (_Float16)x.y; h.z = (_Float16)x.z; h.w = (_Float16)x.w;
    ((f16x4*)Vh)[idx] = h;
}

// ---------- kernel 4: flash attention v4 — LDS-staged K/V, XOR-swizzled ----------
// 256 blocks (1/CU) x 8 waves. QBLK=32 q-rows/block; per KVT=64 tile waves split
// (wq=w&1 q-half, wk=w>>1 kv-quarter). K single-buffered LDS, V dbuf, P LDS.
// Stage loads issued at iter top (coalesced flat), ds_write after barrier 1.
__global__ __launch_bounds__(512, 2)
void attn_kernel(const _Float16* __restrict__ Qh, const _Float16* __restrict__ Kh,
                 const _Float16* __restrict__ Vh, float* __restrict__ out) {
    __shared__ __align__(16) _Float16 Qlds[32][256];      // 16 KB
    __shared__ __align__(16) _Float16 Kst[64][256];       // 32 KB
    __shared__ __align__(16) _Float16 Vst[2][256][64];    // 64 KB
    __shared__ __align__(16) _Float16 Pbuf[32][64];       // 4 KB
    __shared__ float mpart[4][32];
    __shared__ float lbuf[8][16];

    const int tid  = threadIdx.x;
    const int w    = tid >> 6;            // 0..7
    const int lane = tid & 63;
    const int q    = lane & 15;
    const int g    = lane >> 4;
    const int wq   = w & 1;               // q-half
    const int wk   = w >> 1;              // kv-quarter
    const int swz  = q & 7;               // XOR bank swizzle key

    // XCD swizzle: 32 blocks per XCD on same batch -> K+V (4MiB) fits that L2
    const int xb = blockIdx.x & 7;
    const int ib = blockIdx.x >> 3;       // 0..31
    const int b  = xb >> 2;
    const int q0 = ((xb & 3) * 32 + ib) * 32;

    const _Float16* Qp = Qh + ((size_t)(b * NTOK + q0)) * DIM;
    const _Float16* Kp = Kh + (size_t)b * NTOK * DIM;
    const _Float16* Vp = Vh + (size_t)b * NTOK * DIM;

    // ---- prologue: stage Q, K(0), V(0) (flat, fully coalesced, swizzled) ----
#pragma unroll
    for (int j = 0; j < 2; j++) {
        int f = j * 512 + tid; int r = f >> 5, ch = f & 31;
        *(f16x8*)(&Qlds[r][(ch ^ (r & 7)) * 8]) = *(const f16x8*)(Qp + f * 8);
    }
#pragma unroll
    for (int j = 0; j < 4; j++) {
        int f = j * 512 + tid; int r = f >> 5, ch = f & 31;
        *(f16x8*)(&Kst[r][(ch ^ (r & 7)) * 8]) = *(const f16x8*)(Kp + f * 8);
    }
#pragma unroll
    for (int j = 0; j < 4; j++) {
        int f = j * 512 + tid; int c = f >> 3, ch = f & 7;
        *(f16x8*)(&Vst[0][c][(ch ^ (c & 7)) * 8]) = *(const f16x8*)(Vp + (size_t)c * NTOK + ch * 8);
    }
    __syncthreads();

    // Q B-frags for this wave's q-half (32 VGPR)
    f16x8 qf[8];
#pragma unroll
    for (int ks = 0; ks < 8; ks++)
        qf[ks] = *(const f16x8*)(&Qlds[wq * 16 + q][(((ks << 2) + g) ^ swz) * 8]);

    f32x4 of[2][2];                       // [cb][qb]; c = 32w+16cb+4g+i
#pragma unroll
    for (int cb = 0; cb < 2; cb++)
#pragma unroll
        for (int qb = 0; qb < 2; qb++)
            of[cb][qb] = (f32x4){0.f, 0.f, 0.f, 0.f};
    float m0 = -1e30f, m1 = -1e30f;
    float l = 0.f;                        // partial for (q-half wq, kv-quarter wk)

#pragma unroll 1
    for (int t = 0; t < NT; ++t) {
        // ---- A: issue global loads for tile t+1 (consumed as ds_write in C) ----
        int tn = (t + 1 < NT) ? t + 1 : NT - 1;
        f16x8 kreg[4], vreg[4];
#pragma unroll
        for (int j = 0; j < 4; j++) {
            int f = j * 512 + tid;
            kreg[j] = *(const f16x8*)(Kp + (size_t)tn * KVT * DIM + f * 8);
        }
#pragma unroll
        for (int j = 0; j < 4; j++) {
            int f = j * 512 + tid; int c = f >> 3, ch = f & 7;
            vreg[j] = *(const f16x8*)(Vp + (size_t)c * NTOK + tn * KVT + ch * 8);
        }
        // ---- B: QK for (kv-quarter wk) x (q-half wq) ----
        f32x4 sc = (f32x4){0.f, 0.f, 0.f, 0.f};
#pragma unroll
        for (int ks = 0; ks < 8; ks++) {
            f16x8 kf = *(const f16x8*)(&Kst[wk * 16 + q][(((ks << 2) + g) ^ swz) * 8]);
            sc = __builtin_amdgcn_mfma_f32_16x16x32_f16(kf, qf[ks], sc, 0, 0, 0);
        }
        float tm = fmaxf(fmaxf(sc[0], sc[1]), fmaxf(sc[2], sc[3]));
        tm = fmaxf(tm, __shfl_xor(tm, 16));
        tm = fmaxf(tm, __shfl_xor(tm, 32));
        if (lane < 16) mpart[wk][wq * 16 + lane] = tm;
        asm volatile("s_waitcnt lgkmcnt(0)" ::: "memory");
        __builtin_amdgcn_s_barrier();                     // b1
        // ---- C: shared max, softmax, P write, stage K(t+1)/V(t+1), rescale ----
        float mt0 = mpart[0][q], mt1 = mpart[0][16 + q];
#pragma unroll
        for (int kk = 1; kk < 4; kk++) {
            mt0 = fmaxf(mt0, mpart[kk][q]);
            mt1 = fmaxf(mt1, mpart[kk][16 + q]);
        }
        float mn0 = fmaxf(m0, mt0), mn1 = fmaxf(m1, mt1);
        float cf0 = exp2f(m0 - mn0), cf1 = exp2f(m1 - mn1);
        m0 = mn0; m1 = mn1;
        float mno = wq ? mn1 : mn0;
        float p0 = exp2f(sc[0] - mno), p1 = exp2f(sc[1] - mno);
        float p2 = exp2f(sc[2] - mno), p3 = exp2f(sc[3] - mno);
        float ls = (p0 + p1) + (p2 + p3);
        ls += __shfl_xor(ls, 16);
        ls += __shfl_xor(ls, 32);
        l = l * (wq ? cf1 : cf0) + ls;
        {   // P[row=16wq+q][col=16wk+4g .. +3], swizzled 16B chunk, b64 write
            int pch = ((wk << 1) + (g >> 1)) ^ swz;
            u32x2 pk; pk.x = pkh(p0, p1); pk.y = pkh(p2, p3);
            *(u32x2*)((char*)&Pbuf[0][0] + (wq * 16 + q) * 128 + pch * 16 + (g & 1) * 8) = pk;
        }
#pragma unroll
        for (int j = 0; j < 4; j++) {
            int f = j * 512 + tid; int r = f >> 5, ch = f & 31;
            *(f16x8*)(&Kst[r][(ch ^ (r & 7)) * 8]) = kreg[j];
        }
        {
            _Float16 (*Vn)[64] = Vst[(t + 1) & 1];
#pragma unroll
            for (int j = 0; j < 4; j++) {
                int f = j * 512 + tid; int c = f >> 3, ch = f & 7;
                *(f16x8*)(&Vn[c][(ch ^ (c & 7)) * 8]) = vreg[j];
            }
        }
#pragma unroll
        for (int i = 0; i < 4; i++) {
            of[0][0][i] *= cf0; of[0][1][i] *= cf1;
            of[1][0][i] *= cf0; of[1][1][i] *= cf1;
        }
        asm volatile("s_waitcnt lgkmcnt(0)" ::: "memory");
        __builtin_amdgcn_s_barrier();                     // b2
        // ---- D: PV, c-slice [32w, 32w+32) ----
        {
            _Float16 (*Vc)[64] = Vst[t & 1];
#pragma unroll
            for (int ks = 0; ks < 2; ks++) {
                int ch = (((ks << 2) + g) ^ swz) * 8;
                f16x8 pf0 = *(const f16x8*)(&Pbuf[q][ch]);
                f16x8 pf1 = *(const f16x8*)(&Pbuf[16 + q][ch]);
#pragma unroll
                for (int cb = 0; cb < 2; cb++) {
                    f16x8 vf = *(const f16x8*)(&Vc[w * 32 + cb * 16 + q][ch]);
                    of[cb][0] = __builtin_amdgcn_mfma_f32_16x16x32_f16(vf, pf0, of[cb][0], 0, 0, 0);
                    of[cb][1] = __builtin_amdgcn_mfma_f32_16x16x32_f16(vf, pf1, of[cb][1], 0, 0, 0);
                }
            }
        }
    }

    // ---- final: sum per-(half,quarter) l partials ----
    if (lane < 16) lbuf[w][lane] = l;
    __syncthreads();
    float linv0, linv1;
    {
        float s0 = (lbuf[0][q] + lbuf[2][q]) + (lbuf[4][q] + lbuf[6][q]);
        float s1 = (lbuf[1][q] + lbuf[3][q]) + (lbuf[5][q] + lbuf[7][q]);
        linv0 = 1.f / s0; linv1 = 1.f / s1;
    }
    // ---- epilogue: each wave stores its c-slice ----
    float* Ob = out + ((size_t)(b * NTOK + q0)) * DIM;
#pragma unroll
    for (int cb = 0; cb < 2; cb++)
#pragma unroll
        for (int qb = 0; qb < 2; qb++) {
            float inv = qb ? linv1 : linv0;
            float4 o;
            o.x = of[cb][qb][0] * inv;
            o.y = of[cb][qb][1] * inv;
            o.z = of[cb][qb][2] * inv;
            o.w = of[cb][qb][3] * inv;
            *(float4*)(Ob + (size_t)(qb * 16 + q) * DIM + w * 32 + cb * 16 + g * 4) = o;
        }
}

// ---------- launcher ----------
extern "C" void kernel_launch(void* const* d_in, const int* in_sizes, int n_in,
                              void* d_out, int out_size, void* d_ws, size_t ws_size,
                              hipStream_t stream) {
    const float* qin = (const float*)d_in[0];
    const float* kin = (const float*)d_in[1];
    const float* vin = (const float*)d_in[2];
    float* outp = (float*)d_out;

    char* ws = (char*)d_ws;
    float*    pe = (float*)ws;                                   // 64 KB
    _Float16* Qh = (_Float16*)(ws + 65536);                      // 4 MiB
    _Float16* Kh = (_Float16*)(ws + 65536 + (1u << 22));         // 4 MiB
    _Float16* Vh = (_Float16*)(ws + 65536 + (2u << 22));         // 4 MiB

    pe_kernel<<<dim3(64), dim3(256), 0, stream>>>(pe);
    prep_qk_kernel<<<dim3(128, 4, 4), dim3(256), 0, stream>>>(qin, kin, pe, Qh, Kh);
    prep_v_kernel<<<dim3(2048), dim3(256), 0, stream>>>(vin, Vh);
    attn_kernel<<<dim3(256), dim3(512), 0, stream>>>(Qh, Kh, Vh, outp);
}